// Round 1
// baseline (2557.575 us; speedup 1.0000x reference)
//
#include <hip/hip_runtime.h>

// Problem constants (from reference)
#define NPTS   8192   // N
#define NPT    2048   // NPOINT
#define NS     32     // NSAMPLE
#define CIN    64
#define BATCH  4
// threshold: f32 nearest to 0.64 (numpy/jax weak-type the python float 0.8**2 to f32)
#define R2     0.64f

#define NWORK  252    // worker blocks (grid 256 = 4 fps + 252 workers = #CUs)
#define NQUAD  2048   // 8192 centers / 4 per quad

// ---------------- prep: transpose weights into ws ----------------
__global__ __launch_bounds__(256) void prep_kernel(const float* __restrict__ w1,
                                                   const float* __restrict__ w2,
                                                   float* __restrict__ w1t,
                                                   float* __restrict__ w2t) {
  int i = blockIdx.x * 256 + threadIdx.x;
  if (i < 128 * 67) {
    int o = i / 67, c = i % 67;
    w1t[c * 128 + o] = w1[i];
  }
  if (i < 256 * 128) {
    int o = i >> 7, c = i & 127;
    w2t[c * 256 + o] = w2[i];
  }
}

// ---------------- prep_t: transpose feat (B,C,N) -> FT (B,N,C) ----------------
__global__ __launch_bounds__(256) void prep_t_kernel(const float* __restrict__ feat,
                                                     float* __restrict__ FT) {
  const int b = blockIdx.x >> 7;
  const int n0 = (blockIdx.x & 127) << 6;
  const int tid = threadIdx.x;
  __shared__ float T[64][65];

  const float* F = feat + (size_t)b * CIN * NPTS;
#pragma unroll
  for (int p = 0; p < 16; ++p) {
    int c = p * 4 + (tid >> 6), ln = tid & 63;
    T[c][ln] = F[(size_t)c * NPTS + n0 + ln];
  }
  __syncthreads();
  float* O = FT + (size_t)b * NPTS * CIN;
#pragma unroll
  for (int p = 0; p < 4; ++p) {
    int j = tid >> 2, q = (tid & 3) + p * 4;
    float4 v = make_float4(T[q * 4 + 0][j], T[q * 4 + 1][j],
                           T[q * 4 + 2][j], T[q * 4 + 3][j]);
    *(float4*)&O[(size_t)(n0 + j) * CIN + q * 4] = v;
  }
}

// ---------------- Morton sort (u32 keys, in-LDS bitonic) ----------------
__device__ inline uint32_t part1by2(uint32_t x) {
  x &= 1023u;
  x = (x | (x << 16)) & 0x030000FFu;
  x = (x | (x << 8))  & 0x0300F00Fu;
  x = (x | (x << 4))  & 0x030C30C3u;
  x = (x | (x << 2))  & 0x09249249u;
  return x;
}

__device__ inline uint32_t morton3(float x, float y, float z) {
  int qx = (int)((x + 16.f) * 32.f);
  int qy = (int)((y + 16.f) * 32.f);
  int qz = (int)((z + 16.f) * 32.f);
  qx = qx < 0 ? 0 : (qx > 1023 ? 1023 : qx);
  qy = qy < 0 ? 0 : (qy > 1023 ? 1023 : qy);
  qz = qz < 0 ? 0 : (qz > 1023 ? 1023 : qz);
  return part1by2((uint32_t)qx) | (part1by2((uint32_t)qy) << 1) | (part1by2((uint32_t)qz) << 2);
}

__global__ __launch_bounds__(1024) void sort_kernel(const float* __restrict__ xyz,
                                                    float4* __restrict__ sorted) {
  const int b = blockIdx.x;
  const int tid = threadIdx.x;
  const float* X = xyz + (size_t)b * NPTS * 3;
  __shared__ uint32_t S[NPTS];  // 32 KB

  for (int k = 0; k < 8; ++k) {
    int p = tid + (k << 10);
    uint32_t m = morton3(X[p * 3 + 0], X[p * 3 + 1], X[p * 3 + 2]);
    S[p] = ((m >> 11) << 13) | (uint32_t)p;
  }
  __syncthreads();
  for (unsigned k = 2; k <= NPTS; k <<= 1) {
    for (unsigned j = k >> 1; j > 0; j >>= 1) {
      for (int i = tid; i < NPTS; i += 1024) {
        int l = i ^ (int)j;
        if (l > i) {
          uint32_t a = S[i], c = S[l];
          bool sw = ((i & k) == 0) ? (a > c) : (a < c);
          if (sw) { S[i] = c; S[l] = a; }
        }
      }
      __syncthreads();
    }
  }
  for (int k = 0; k < 8; ++k) {
    int pos = tid + (k << 10);
    int o = (int)(S[pos] & 8191u);
    float4 v;
    v.x = X[o * 3 + 0]; v.y = X[o * 3 + 1]; v.z = X[o * 3 + 2];
    v.w = __int_as_float(o);
    sorted[(size_t)b * NPTS + pos] = v;
  }
}

// ---------------- fused FPS + (ballquery + group + MLP + pool) workers --------
// Blocks 0..3: FPS loop (bit-exact selection math identical to verified R7/R10),
//   with two latency/throughput changes:
//   (a) WAVE-level bbox prune: per-thread `if(act)` only saves issue cycles when
//       the WHOLE wave's exec mask is 0 (s_cbranch_execz), so the effective
//       prune granularity was always the wave. Test it explicitly: skip the
//       entire update+reduce when dist2(center, wave_bbox)*0.9999 >= wave's
//       current max dmin (wwmf). Sound: thread bbox subset of wave bbox and
//       cmaxv_t <= wwmf, so wave-skip implies every thread would self-skip.
//   (b) winner coords broadcast through rec (recc + v_readlane) instead of the
//       dependent XL[3*sidx] LDS read; coords are the same exact float bits
//       (copies of X), so results stay bit-identical. XL table removed.
// Blocks 4..255: persistent workers, unchanged.

#define DPP_ROR_U32_MAX(v)                                                       \
  {                                                                              \
    uint32_t _t;                                                                 \
    _t = (uint32_t)__builtin_amdgcn_update_dpp(0, (int)(v), 0x121, 0xF, 0xF, false); if (_t > (v)) (v) = _t; \
    _t = (uint32_t)__builtin_amdgcn_update_dpp(0, (int)(v), 0x122, 0xF, 0xF, false); if (_t > (v)) (v) = _t; \
    _t = (uint32_t)__builtin_amdgcn_update_dpp(0, (int)(v), 0x124, 0xF, 0xF, false); if (_t > (v)) (v) = _t; \
    _t = (uint32_t)__builtin_amdgcn_update_dpp(0, (int)(v), 0x128, 0xF, 0xF, false); if (_t > (v)) (v) = _t; \
  }

#define DPP_ROR_U32_MIN(v)                                                       \
  {                                                                              \
    uint32_t _t;                                                                 \
    _t = (uint32_t)__builtin_amdgcn_update_dpp(-1, (int)(v), 0x121, 0xF, 0xF, false); if (_t < (v)) (v) = _t; \
    _t = (uint32_t)__builtin_amdgcn_update_dpp(-1, (int)(v), 0x122, 0xF, 0xF, false); if (_t < (v)) (v) = _t; \
    _t = (uint32_t)__builtin_amdgcn_update_dpp(-1, (int)(v), 0x124, 0xF, 0xF, false); if (_t < (v)) (v) = _t; \
    _t = (uint32_t)__builtin_amdgcn_update_dpp(-1, (int)(v), 0x128, 0xF, 0xF, false); if (_t < (v)) (v) = _t; \
  }

#define CSWAP(i, j)                                                              \
  if (oid[i] > oid[j]) {                                                         \
    int _ti = oid[i]; oid[i] = oid[j]; oid[j] = _ti;                             \
    float _tf;                                                                   \
    _tf = px[i]; px[i] = px[j]; px[j] = _tf;                                     \
    _tf = py[i]; py[i] = py[j]; py[j] = _tf;                                     \
    _tf = pz[i]; pz[i] = pz[j]; pz[j] = _tf;                                     \
  }

__global__ __launch_bounds__(1024, 1) void fused_kernel(
    const float* __restrict__ xyz, const float4* __restrict__ sorted,
    const float* __restrict__ FT,
    const float* __restrict__ w1t, const float* __restrict__ b1,
    const float* __restrict__ w2t, const float* __restrict__ b2,
    float* __restrict__ new_xyz, float* __restrict__ pooled,
    int* __restrict__ progress) {
  const int tid = threadIdx.x;
  const int lane = tid & 63;
  const int wv = tid >> 6;

  __shared__ __align__(16) char SM[100416];   // ~100 KB -> 1 block/CU

  if (blockIdx.x < 4) {
    // ================= FPS role =================
    const int b = blockIdx.x;
    uint2  (*rec)[16]  = (uint2(*)[16])(SM + 98304);    // [2][16] (wm, wi)
    float4 (*recc)[16] = (float4(*)[16])(SM + 98560);   // [2][16] winner coords
    const float* X = xyz + (size_t)b * NPTS * 3;
    const float4* SP = sorted + (size_t)b * NPTS;

    float px[8], py[8], pz[8], dmin[8];
    int oid[8];
#pragma unroll
    for (int k = 0; k < 8; ++k) {
      float4 p = SP[tid * 8 + k];
      px[k] = p.x; py[k] = p.y; pz[k] = p.z;
      oid[k] = __float_as_int(p.w);
      dmin[k] = 1e10f;
    }
    CSWAP(0, 1) CSWAP(2, 3) CSWAP(4, 5) CSWAP(6, 7)
    CSWAP(0, 2) CSWAP(1, 3) CSWAP(4, 6) CSWAP(5, 7)
    CSWAP(1, 2) CSWAP(5, 6)
    CSWAP(0, 4) CSWAP(1, 5) CSWAP(2, 6) CSWAP(3, 7)
    CSWAP(2, 4) CSWAP(3, 5)
    CSWAP(1, 2) CSWAP(3, 4) CSWAP(5, 6)

    float bxmin = px[0], bxmax = px[0], bymin = py[0], bymax = py[0], bzmin = pz[0], bzmax = pz[0];
#pragma unroll
    for (int k = 1; k < 8; ++k) {
      bxmin = fminf(bxmin, px[k]); bxmax = fmaxf(bxmax, px[k]);
      bymin = fminf(bymin, py[k]); bymax = fmaxf(bymax, py[k]);
      bzmin = fminf(bzmin, pz[k]); bzmax = fmaxf(bzmax, pz[k]);
    }
    // wave-level bbox (uniform across the wave after butterfly reduce)
    float wbxmin = bxmin, wbxmax = bxmax;
    float wbymin = bymin, wbymax = bymax;
    float wbzmin = bzmin, wbzmax = bzmax;
#pragma unroll
    for (int off = 1; off < 64; off <<= 1) {
      wbxmin = fminf(wbxmin, __shfl_xor(wbxmin, off));
      wbxmax = fmaxf(wbxmax, __shfl_xor(wbxmax, off));
      wbymin = fminf(wbymin, __shfl_xor(wbymin, off));
      wbymax = fmaxf(wbymax, __shfl_xor(wbymax, off));
      wbzmin = fminf(wbzmin, __shfl_xor(wbzmin, off));
      wbzmax = fmaxf(wbzmax, __shfl_xor(wbzmax, off));
    }

    float cmaxv = 1e10f;
    int   cmaxi = oid[0];
    uint32_t wwm = 0u, wwi = 0u;
    float wwmf = 1e10f;          // wave's current max dmin (float view of wwm)
    bool  iswin = false;         // this lane holds the wave's current winner
    float wwx = 0.f, wwy = 0.f, wwz = 0.f;

    float cx = X[0], cy = X[1], cz = X[2];
    if (tid == 0) {
      new_xyz[(size_t)b * NPT * 3 + 0] = cx;
      new_xyz[(size_t)b * NPT * 3 + 1] = cy;
      new_xyz[(size_t)b * NPT * 3 + 2] = cz;
    }
    __syncthreads();

    for (int t = 1; t < NPT; ++t) {
      // ---- wave-level prune: skip whole update+reduce if center provably far
      float exw = fmaxf(fmaxf(wbxmin - cx, cx - wbxmax), 0.f);
      float eyw = fmaxf(fmaxf(wbymin - cy, cy - wbymax), 0.f);
      float ezw = fmaxf(fmaxf(wbzmin - cz, cz - wbzmax), 0.f);
      float dlbw = (exw * exw + eyw * eyw + ezw * ezw) * 0.9999f;

      if (dlbw < wwmf) {
        float ex = fmaxf(fmaxf(bxmin - cx, cx - bxmax), 0.f);
        float ey = fmaxf(fmaxf(bymin - cy, cy - bymax), 0.f);
        float ez = fmaxf(fmaxf(bzmin - cz, cz - bzmax), 0.f);
        float dlb = (ex * ex + ey * ey + ez * ez) * 0.9999f;
        bool act = dlb < cmaxv;

        if (__ballot(act)) {
          if (act) {
            float mv = -1.0f; int mi = 0;
#pragma unroll
            for (int k = 0; k < 8; ++k) {
              float dx = px[k] - cx, dy = py[k] - cy, dz = pz[k] - cz;
              float d = __fadd_rn(__fadd_rn(__fmul_rn(dx, dx), __fmul_rn(dy, dy)), __fmul_rn(dz, dz));
              float dm = fminf(dmin[k], d);
              dmin[k] = dm;
              if (dm > mv) { mv = dm; mi = oid[k]; }
            }
            cmaxv = mv; cmaxi = mi;
          }
          uint32_t vb = __float_as_uint(cmaxv);
          uint32_t rm = vb;
          DPP_ROR_U32_MAX(rm)
          uint32_t m0 = (uint32_t)__builtin_amdgcn_readlane((int)rm, 0);
          uint32_t m1 = (uint32_t)__builtin_amdgcn_readlane((int)rm, 16);
          uint32_t m2 = (uint32_t)__builtin_amdgcn_readlane((int)rm, 32);
          uint32_t m3 = (uint32_t)__builtin_amdgcn_readlane((int)rm, 48);
          uint32_t wm = m0 > m1 ? m0 : m1;
          uint32_t wmb = m2 > m3 ? m2 : m3;
          wm = wm > wmb ? wm : wmb;
          unsigned long long em = __ballot(vb == wm);
          uint32_t wi;
          if (__popcll(em) == 1) {
            wi = (uint32_t)__builtin_amdgcn_readlane(cmaxi, __ffsll(em) - 1);
          } else {
            uint32_t ik = (vb == wm) ? (uint32_t)cmaxi : 0xFFFFFFFFu;
            DPP_ROR_U32_MIN(ik)
            uint32_t i0 = (uint32_t)__builtin_amdgcn_readlane((int)ik, 0);
            uint32_t i1 = (uint32_t)__builtin_amdgcn_readlane((int)ik, 16);
            uint32_t i2 = (uint32_t)__builtin_amdgcn_readlane((int)ik, 32);
            uint32_t i3 = (uint32_t)__builtin_amdgcn_readlane((int)ik, 48);
            wi = i0 < i1 ? i0 : i1;
            uint32_t wib = i2 < i3 ? i2 : i3;
            wi = wi < wib ? wi : wib;
          }
          wwm = wm; wwi = wi;
          wwmf = __uint_as_float(wm);
          // winner lane caches its winner's exact coords (unique oid -> one lane)
          iswin = (vb == wm) && ((uint32_t)cmaxi == wi);
          if (iswin) {
#pragma unroll
            for (int k = 0; k < 8; ++k)
              if (oid[k] == (int)wi) { wwx = px[k]; wwy = py[k]; wwz = pz[k]; }
          }
        }
      }

      const int buf = t & 1;
      if (lane == 0) { rec[buf][wv].x = wwm; rec[buf][wv].y = wwi; }
      if (iswin)     { recc[buf][wv] = make_float4(wwx, wwy, wwz, 0.f); }
      __syncthreads();

      uint2  r  = rec[buf][lane & 15];
      float4 rc = recc[buf][lane & 15];
      uint32_t bm = r.x;
      DPP_ROR_U32_MAX(bm)
      // pack (oid<<4)|wave: oid unique across waves, so ordering == oid ordering
      uint32_t ci = (r.x == bm) ? ((r.y << 4) | (uint32_t)(lane & 15)) : 0xFFFFFFFFu;
      DPP_ROR_U32_MIN(ci)
      int s = __builtin_amdgcn_readfirstlane((int)ci);
      int wl = s & 15;
      cx = __int_as_float(__builtin_amdgcn_readlane(__float_as_int(rc.x), wl));
      cy = __int_as_float(__builtin_amdgcn_readlane(__float_as_int(rc.y), wl));
      cz = __int_as_float(__builtin_amdgcn_readlane(__float_as_int(rc.z), wl));

      if (tid == 0) {
        float* o = new_xyz + ((size_t)b * NPT + t) * 3;
        o[0] = cx; o[1] = cy; o[2] = cz;
        if ((t & 15) == 15)   // includes t=2047
          __hip_atomic_store(progress + b, t, __ATOMIC_RELEASE, __HIP_MEMORY_SCOPE_AGENT);
      }
    }
  } else {
    // ================= worker role: bq + group + MLP + pool =================
    float* G    = (float*)SM;                 // 67 x 128
    float* H1   = (float*)(SM + 34304);       // 128 x 128
    int*   lidx = (int*)(SM + 99840);         // 4 x 32
    float* ctr  = (float*)(SM + 100352);      // 4 x 3

    const int wbid = blockIdx.x - 4;          // 0..251

    for (int qg = wbid; qg < NQUAD; qg += NWORK) {
      const int b = qg & 3;                   // quads ordered by squad -> readiness-monotone
      const int s0 = (qg >> 2) * 4;           // first center (in-batch), 4 per quad
      const float* X  = xyz + (size_t)b * NPTS * 3;
      const float* Fp = FT + (size_t)b * NPTS * CIN;

      // 1) wait for fps to produce centers s0..s0+3
      if (tid == 0) {
        while (__hip_atomic_load(progress + b, __ATOMIC_ACQUIRE, __HIP_MEMORY_SCOPE_AGENT) < s0 + 3)
          __builtin_amdgcn_s_sleep(2);
      }
      __syncthreads();

      // 2) centers -> LDS; ball query: one wave per center (waves 0..3)
      if (tid < 12) ctr[tid] = new_xyz[((size_t)b * NPT + s0) * 3 + tid];
      if (wv < 4) {
        const int s = s0 + wv;
        const float cx = new_xyz[((size_t)b * NPT + s) * 3 + 0];
        const float cy = new_xyz[((size_t)b * NPT + s) * 3 + 1];
        const float cz = new_xyz[((size_t)b * NPT + s) * 3 + 2];
        int* out = lidx + wv * NS;
        int found = 0;
        int first = -1;
        for (int base = 0; base < NPTS; base += 64) {
          const int p = base + lane;
          float x = X[p * 3 + 0], y = X[p * 3 + 1], z = X[p * 3 + 2];
          float dx = x - cx, dy = y - cy, dz = z - cz;
          float d2 = __fadd_rn(__fadd_rn(__fmul_rn(dx, dx), __fmul_rn(dy, dy)), __fmul_rn(dz, dz));
          unsigned long long mask = __ballot(d2 < R2);
          if (mask != 0ull && first < 0) first = base + __ffsll((unsigned long long)mask) - 1;
          if (found < NS) {
            if ((mask >> lane) & 1ull) {
              int rank = found + __popcll(mask & ((1ull << lane) - 1ull));
              if (rank < NS) out[rank] = p;
            }
          }
          found += __popcll(mask);
          if (found >= NS) break;
        }
        if (found < NS) {
          int pad = (first < 0) ? 0 : first;
          if (lane >= found && lane < NS) out[lane] = pad;
        }
      }
      __syncthreads();

      // 3) G fill: feature rows via point-major FT (coalesced), rel-xyz rows
      {
        int j = tid >> 3, q = tid & 7;       // 128 points x 8 chunks
        int p = lidx[j];
        const float4* row = (const float4*)(Fp + (size_t)p * CIN);
        float4 v0 = row[q * 2 + 0];
        float4 v1 = row[q * 2 + 1];
        float vs[8] = {v0.x, v0.y, v0.z, v0.w, v1.x, v1.y, v1.z, v1.w};
#pragma unroll
        for (int i = 0; i < 8; ++i)
          G[(3 + q * 8 + i) * 128 + j] = vs[i];
      }
      if (tid < 384) {
        int c = tid >> 7, j = tid & 127;
        int p = lidx[j];
        G[c * 128 + j] = X[p * 3 + c] - ctr[(j >> 5) * 3 + c];
      }
      __syncthreads();

      // 4) H1 = relu(W1 @ G + b1): 128 x 128, each thread 4o x 4j
      {
        const int oi = tid >> 5, ji = tid & 31;
        const int o0 = oi * 4, j0 = ji * 4;
        float acc[4][4];
#pragma unroll
        for (int i = 0; i < 4; ++i)
#pragma unroll
          for (int jj = 0; jj < 4; ++jj) acc[i][jj] = 0.f;
#pragma unroll 4
        for (int c = 0; c < 67; ++c) {
          float4 g  = *(const float4*)&G[c * 128 + j0];
          float4 wf = *(const float4*)&w1t[c * 128 + o0];
          float ga[4] = {g.x, g.y, g.z, g.w};
          float wa[4] = {wf.x, wf.y, wf.z, wf.w};
#pragma unroll
          for (int i = 0; i < 4; ++i)
#pragma unroll
            for (int jj = 0; jj < 4; ++jj)
              acc[i][jj] = fmaf(wa[i], ga[jj], acc[i][jj]);
        }
        float4 bb = *(const float4*)&b1[o0];
        float ba[4] = {bb.x, bb.y, bb.z, bb.w};
#pragma unroll
        for (int i = 0; i < 4; ++i) {
          float4 h;
          h.x = fmaxf(acc[i][0] + ba[i], 0.f);
          h.y = fmaxf(acc[i][1] + ba[i], 0.f);
          h.z = fmaxf(acc[i][2] + ba[i], 0.f);
          h.w = fmaxf(acc[i][3] + ba[i], 0.f);
          *(float4*)&H1[(o0 + i) * 128 + j0] = h;
        }
      }
      __syncthreads();

      // 5) H2 = relu(W2 @ H1 + b2): 256 x 128, thread 8o x 4j, then maxpool
      {
        const int oi = tid >> 5, ji = tid & 31;
        const int o0 = oi * 8, j0 = ji * 4;
        float acc[8][4];
#pragma unroll
        for (int i = 0; i < 8; ++i)
#pragma unroll
          for (int jj = 0; jj < 4; ++jj) acc[i][jj] = 0.f;
#pragma unroll 2
        for (int c = 0; c < 128; ++c) {
          float4 h  = *(const float4*)&H1[c * 128 + j0];
          float4 wa4 = *(const float4*)&w2t[c * 256 + o0];
          float4 wb4 = *(const float4*)&w2t[c * 256 + o0 + 4];
          float ha[4] = {h.x, h.y, h.z, h.w};
          float wa[8] = {wa4.x, wa4.y, wa4.z, wa4.w, wb4.x, wb4.y, wb4.z, wb4.w};
#pragma unroll
          for (int i = 0; i < 8; ++i)
#pragma unroll
            for (int jj = 0; jj < 4; ++jj)
              acc[i][jj] = fmaf(wa[i], ha[jj], acc[i][jj]);
        }
        float4 b2a = *(const float4*)&b2[o0];
        float4 b2b = *(const float4*)&b2[o0 + 4];
        float bb[8] = {b2a.x, b2a.y, b2a.z, b2a.w, b2b.x, b2b.y, b2b.z, b2b.w};
        float m[8];
#pragma unroll
        for (int i = 0; i < 8; ++i) {
          float v0 = fmaxf(acc[i][0] + bb[i], 0.f);
          float v1 = fmaxf(acc[i][1] + bb[i], 0.f);
          float v2 = fmaxf(acc[i][2] + bb[i], 0.f);
          float v3 = fmaxf(acc[i][3] + bb[i], 0.f);
          m[i] = fmaxf(fmaxf(v0, v1), fmaxf(v2, v3));
        }
        // ji&7 groups (8 lanes x 4 j = 32 samples = one center); xor 1,2,4
        // stays within each 8-lane group.
#pragma unroll
        for (int off = 1; off < 8; off <<= 1)
#pragma unroll
          for (int i = 0; i < 8; ++i) m[i] = fmaxf(m[i], __shfl_xor(m[i], off));
        if ((ji & 7) == 0) {
          int sidx = s0 + (ji >> 3);
#pragma unroll
          for (int i = 0; i < 8; ++i)
            pooled[((size_t)b * 256 + o0 + i) * (size_t)NPT + sidx] = m[i];
        }
      }
    }
  }
}

extern "C" void kernel_launch(void* const* d_in, const int* in_sizes, int n_in,
                              void* d_out, int out_size, void* d_ws, size_t ws_size,
                              hipStream_t stream) {
  (void)in_sizes; (void)n_in; (void)out_size; (void)ws_size;
  const float* xyz  = (const float*)d_in[0];   // (4,8192,3)
  const float* feat = (const float*)d_in[1];   // (4,64,8192)
  const float* w1   = (const float*)d_in[2];   // (128,67)
  const float* b1   = (const float*)d_in[3];   // (128)
  const float* w2   = (const float*)d_in[4];   // (256,128)
  const float* b2   = (const float*)d_in[5];   // (256)

  float* out     = (float*)d_out;
  float* new_xyz = out;                        // (4,2048,3)
  float* pooled  = out + (size_t)BATCH * NPT * 3;  // (4,256,2048)

  char* ws = (char*)d_ws;
  float*  w1t      = (float*)ws;                       // 34304 B
  float*  w2t      = (float*)(ws + 34304);             // 131072 B -> 165376
  float4* sorted   = (float4*)(ws + 165376);           // 524288 B -> 689664
  float*  FT       = (float*)(ws + 689664);            // 8388608 B -> 9078272
  int*    progress = (int*)(ws + 9078272);             // 16 B

  prep_kernel<<<128, 256, 0, stream>>>(w1, w2, w1t, w2t);
  prep_t_kernel<<<BATCH * 128, 256, 0, stream>>>(feat, FT);
  sort_kernel<<<BATCH, 1024, 0, stream>>>(xyz, sorted);
  (void)hipMemsetAsync(progress, 0, 16, stream);
  fused_kernel<<<256, 1024, 0, stream>>>(xyz, sorted, FT, w1t, b1, w2t, b2,
                                         new_xyz, pooled, progress);
}

// Round 2
// 1956.068 us; speedup vs baseline: 1.3075x; 1.3075x over previous
//
#include <hip/hip_runtime.h>

// Problem constants (from reference)
#define NPTS   8192   // N
#define NPT    2048   // NPOINT
#define NS     32     // NSAMPLE
#define CIN    64
#define BATCH  4
// threshold: f32 nearest to 0.64 (numpy/jax weak-type the python float 0.8**2 to f32)
#define R2     0.64f

#define NWORK  252    // worker blocks (grid 256 = 4 fps + 252 workers = #CUs)
#define NQUAD  2048   // 8192 centers / 4 per quad

typedef float __attribute__((ext_vector_type(2))) f32x2;

// ---------------- prep: transpose weights into ws ----------------
__global__ __launch_bounds__(256) void prep_kernel(const float* __restrict__ w1,
                                                   const float* __restrict__ w2,
                                                   float* __restrict__ w1t,
                                                   float* __restrict__ w2t) {
  int i = blockIdx.x * 256 + threadIdx.x;
  if (i < 128 * 67) {
    int o = i / 67, c = i % 67;
    w1t[c * 128 + o] = w1[i];
  }
  if (i < 256 * 128) {
    int o = i >> 7, c = i & 127;
    w2t[c * 256 + o] = w2[i];
  }
}

// ---------------- prep_t: transpose feat (B,C,N) -> FT (B,N,C) ----------------
__global__ __launch_bounds__(256) void prep_t_kernel(const float* __restrict__ feat,
                                                     float* __restrict__ FT) {
  const int b = blockIdx.x >> 7;
  const int n0 = (blockIdx.x & 127) << 6;
  const int tid = threadIdx.x;
  __shared__ float T[64][65];

  const float* F = feat + (size_t)b * CIN * NPTS;
#pragma unroll
  for (int p = 0; p < 16; ++p) {
    int c = p * 4 + (tid >> 6), ln = tid & 63;
    T[c][ln] = F[(size_t)c * NPTS + n0 + ln];
  }
  __syncthreads();
  float* O = FT + (size_t)b * NPTS * CIN;
#pragma unroll
  for (int p = 0; p < 4; ++p) {
    int j = tid >> 2, q = (tid & 3) + p * 4;
    float4 v = make_float4(T[q * 4 + 0][j], T[q * 4 + 1][j],
                           T[q * 4 + 2][j], T[q * 4 + 3][j]);
    *(float4*)&O[(size_t)(n0 + j) * CIN + q * 4] = v;
  }
}

// ---------------- Morton sort (u32 keys, in-LDS bitonic) ----------------
__device__ inline uint32_t part1by2(uint32_t x) {
  x &= 1023u;
  x = (x | (x << 16)) & 0x030000FFu;
  x = (x | (x << 8))  & 0x0300F00Fu;
  x = (x | (x << 4))  & 0x030C30C3u;
  x = (x | (x << 2))  & 0x09249249u;
  return x;
}

__device__ inline uint32_t morton3(float x, float y, float z) {
  int qx = (int)((x + 16.f) * 32.f);
  int qy = (int)((y + 16.f) * 32.f);
  int qz = (int)((z + 16.f) * 32.f);
  qx = qx < 0 ? 0 : (qx > 1023 ? 1023 : qx);
  qy = qy < 0 ? 0 : (qy > 1023 ? 1023 : qy);
  qz = qz < 0 ? 0 : (qz > 1023 ? 1023 : qz);
  return part1by2((uint32_t)qx) | (part1by2((uint32_t)qy) << 1) | (part1by2((uint32_t)qz) << 2);
}

__global__ __launch_bounds__(1024) void sort_kernel(const float* __restrict__ xyz,
                                                    float4* __restrict__ sorted) {
  const int b = blockIdx.x;
  const int tid = threadIdx.x;
  const float* X = xyz + (size_t)b * NPTS * 3;
  __shared__ uint32_t S[NPTS];  // 32 KB

  for (int k = 0; k < 8; ++k) {
    int p = tid + (k << 10);
    uint32_t m = morton3(X[p * 3 + 0], X[p * 3 + 1], X[p * 3 + 2]);
    S[p] = ((m >> 11) << 13) | (uint32_t)p;
  }
  __syncthreads();
  for (unsigned k = 2; k <= NPTS; k <<= 1) {
    for (unsigned j = k >> 1; j > 0; j >>= 1) {
      for (int i = tid; i < NPTS; i += 1024) {
        int l = i ^ (int)j;
        if (l > i) {
          uint32_t a = S[i], c = S[l];
          bool sw = ((i & k) == 0) ? (a > c) : (a < c);
          if (sw) { S[i] = c; S[l] = a; }
        }
      }
      __syncthreads();
    }
  }
  for (int k = 0; k < 8; ++k) {
    int pos = tid + (k << 10);
    int o = (int)(S[pos] & 8191u);
    float4 v;
    v.x = X[o * 3 + 0]; v.y = X[o * 3 + 1]; v.z = X[o * 3 + 2];
    v.w = __int_as_float(o);
    sorted[(size_t)b * NPTS + pos] = v;
  }
}

// ---------------- fused FPS + (ballquery + group + MLP + pool) workers --------
// Blocks 0..3: verified R7/R10 FPS loop (bit-exact, absmax 0.0), publishing
//   progress[b]=t (release, agent scope) every 16 centers.
//   R1 change: the 8-point distance update uses packed-FP32 VOP3P
//   (v_pk_add_f32 / v_pk_mul_f32) processing point PAIRS: 8 instr / 2 points
//   instead of 16 scalar. Center is pre-negated so subtraction is a plain
//   pk_add (a + (-c) is IEEE-identical to a - c); mul/add order per element
//   is unchanged -> bit-identical selection. The FPS loop is issue-bound at
//   4 waves/SIMD (2 cyc/instr), so -32 instr/thread/iter in the dominant
//   region is the lever (R0 post-mortem: ADDING ~60 instr cost +58%).
// Blocks 4..255: persistent workers; unchanged.

#define DPP_ROR_U32_MAX(v)                                                       \
  {                                                                              \
    uint32_t _t;                                                                 \
    _t = (uint32_t)__builtin_amdgcn_update_dpp(0, (int)(v), 0x121, 0xF, 0xF, false); if (_t > (v)) (v) = _t; \
    _t = (uint32_t)__builtin_amdgcn_update_dpp(0, (int)(v), 0x122, 0xF, 0xF, false); if (_t > (v)) (v) = _t; \
    _t = (uint32_t)__builtin_amdgcn_update_dpp(0, (int)(v), 0x124, 0xF, 0xF, false); if (_t > (v)) (v) = _t; \
    _t = (uint32_t)__builtin_amdgcn_update_dpp(0, (int)(v), 0x128, 0xF, 0xF, false); if (_t > (v)) (v) = _t; \
  }

#define DPP_ROR_U32_MIN(v)                                                       \
  {                                                                              \
    uint32_t _t;                                                                 \
    _t = (uint32_t)__builtin_amdgcn_update_dpp(-1, (int)(v), 0x121, 0xF, 0xF, false); if (_t < (v)) (v) = _t; \
    _t = (uint32_t)__builtin_amdgcn_update_dpp(-1, (int)(v), 0x122, 0xF, 0xF, false); if (_t < (v)) (v) = _t; \
    _t = (uint32_t)__builtin_amdgcn_update_dpp(-1, (int)(v), 0x124, 0xF, 0xF, false); if (_t < (v)) (v) = _t; \
    _t = (uint32_t)__builtin_amdgcn_update_dpp(-1, (int)(v), 0x128, 0xF, 0xF, false); if (_t < (v)) (v) = _t; \
  }

#define CSWAP(i, j)                                                              \
  if (oid[i] > oid[j]) {                                                         \
    int _ti = oid[i]; oid[i] = oid[j]; oid[j] = _ti;                             \
    float _tf;                                                                   \
    _tf = px[i]; px[i] = px[j]; px[j] = _tf;                                     \
    _tf = py[i]; py[i] = py[j]; py[j] = _tf;                                     \
    _tf = pz[i]; pz[i] = pz[j]; pz[j] = _tf;                                     \
  }

__global__ __launch_bounds__(1024, 1) void fused_kernel(
    const float* __restrict__ xyz, const float4* __restrict__ sorted,
    const float* __restrict__ FT,
    const float* __restrict__ w1t, const float* __restrict__ b1,
    const float* __restrict__ w2t, const float* __restrict__ b2,
    float* __restrict__ new_xyz, float* __restrict__ pooled,
    int* __restrict__ progress) {
  const int tid = threadIdx.x;
  const int lane = tid & 63;
  const int wv = tid >> 6;

  __shared__ __align__(16) char SM[100416];   // ~100 KB -> 1 block/CU

  if (blockIdx.x < 4) {
    // ================= FPS role (R7/R10 body + pk-pair update) =================
    const int b = blockIdx.x;
    float* XL = (float*)SM;                   // 96 KB coord table
    uint2 (*rec)[16] = (uint2(*)[16])(SM + 98304);   // [2][16]
    const float* X = xyz + (size_t)b * NPTS * 3;
    const float4* SP = sorted + (size_t)b * NPTS;

    for (int i = tid; i < NPTS * 3; i += 1024) XL[i] = X[i];

    float px[8], py[8], pz[8];
    int oid[8];
#pragma unroll
    for (int k = 0; k < 8; ++k) {
      float4 p = SP[tid * 8 + k];
      px[k] = p.x; py[k] = p.y; pz[k] = p.z;
      oid[k] = __float_as_int(p.w);
    }
    CSWAP(0, 1) CSWAP(2, 3) CSWAP(4, 5) CSWAP(6, 7)
    CSWAP(0, 2) CSWAP(1, 3) CSWAP(4, 6) CSWAP(5, 7)
    CSWAP(1, 2) CSWAP(5, 6)
    CSWAP(0, 4) CSWAP(1, 5) CSWAP(2, 6) CSWAP(3, 7)
    CSWAP(2, 4) CSWAP(3, 5)
    CSWAP(1, 2) CSWAP(3, 4) CSWAP(5, 6)

    float bxmin = px[0], bxmax = px[0], bymin = py[0], bymax = py[0], bzmin = pz[0], bzmax = pz[0];
#pragma unroll
    for (int k = 1; k < 8; ++k) {
      bxmin = fminf(bxmin, px[k]); bxmax = fmaxf(bxmax, px[k]);
      bymin = fminf(bymin, py[k]); bymax = fmaxf(bymax, py[k]);
      bzmin = fminf(bzmin, pz[k]); bzmax = fmaxf(bzmax, pz[k]);
    }

    // pack points into pairs for VOP3P packed-f32 math (order preserved)
    f32x2 px2[4], py2[4], pz2[4], dm2[4];
#pragma unroll
    for (int j = 0; j < 4; ++j) {
      px2[j] = f32x2{px[2 * j], px[2 * j + 1]};
      py2[j] = f32x2{py[2 * j], py[2 * j + 1]};
      pz2[j] = f32x2{pz[2 * j], pz[2 * j + 1]};
      dm2[j] = f32x2{1e10f, 1e10f};
    }

    float cmaxv = 1e10f;
    int   cmaxi = oid[0];
    uint32_t wwm = 0u, wwi = 0u;

    float cx = X[0], cy = X[1], cz = X[2];
    if (tid == 0) {
      new_xyz[(size_t)b * NPT * 3 + 0] = cx;
      new_xyz[(size_t)b * NPT * 3 + 1] = cy;
      new_xyz[(size_t)b * NPT * 3 + 2] = cz;
    }
    __syncthreads();   // XL ready

    for (int t = 1; t < NPT; ++t) {
      float ex = fmaxf(fmaxf(bxmin - cx, cx - bxmax), 0.f);
      float ey = fmaxf(fmaxf(bymin - cy, cy - bymax), 0.f);
      float ez = fmaxf(fmaxf(bzmin - cz, cz - bzmax), 0.f);
      float dlb = (ex * ex + ey * ey + ez * ez) * 0.9999f;
      bool act = dlb < cmaxv;

      if (__ballot(act)) {
        if (act) {
          // negated center, broadcast into both packed halves:
          // a + (-c) is bit-identical to a - c (IEEE f32, rn)
          const float ncx = -cx, ncy = -cy, ncz = -cz;
          const f32x2 ncx2 = f32x2{ncx, ncx};
          const f32x2 ncy2 = f32x2{ncy, ncy};
          const f32x2 ncz2 = f32x2{ncz, ncz};
          float mv = -1.0f; int mi = 0;
#pragma unroll
          for (int j = 0; j < 4; ++j) {
            f32x2 dx2, dy2, dz2, xx2, yy2, zz2, s2, dd2;
            asm("v_pk_add_f32 %0, %1, %2" : "=v"(dx2) : "v"(px2[j]), "v"(ncx2));
            asm("v_pk_add_f32 %0, %1, %2" : "=v"(dy2) : "v"(py2[j]), "v"(ncy2));
            asm("v_pk_add_f32 %0, %1, %2" : "=v"(dz2) : "v"(pz2[j]), "v"(ncz2));
            asm("v_pk_mul_f32 %0, %1, %1" : "=v"(xx2) : "v"(dx2));
            asm("v_pk_mul_f32 %0, %1, %1" : "=v"(yy2) : "v"(dy2));
            asm("v_pk_mul_f32 %0, %1, %1" : "=v"(zz2) : "v"(dz2));
            asm("v_pk_add_f32 %0, %1, %2" : "=v"(s2) : "v"(xx2), "v"(yy2));
            asm("v_pk_add_f32 %0, %1, %2" : "=v"(dd2) : "v"(s2), "v"(zz2));
            float m0 = fminf(dm2[j].x, dd2.x);
            float m1 = fminf(dm2[j].y, dd2.y);
            dm2[j].x = m0; dm2[j].y = m1;
            if (m0 > mv) { mv = m0; mi = oid[2 * j]; }
            if (m1 > mv) { mv = m1; mi = oid[2 * j + 1]; }
          }
          cmaxv = mv; cmaxi = mi;
        }
        uint32_t vb = __float_as_uint(cmaxv);
        uint32_t rm = vb;
        DPP_ROR_U32_MAX(rm)
        uint32_t m0 = (uint32_t)__builtin_amdgcn_readlane((int)rm, 0);
        uint32_t m1 = (uint32_t)__builtin_amdgcn_readlane((int)rm, 16);
        uint32_t m2 = (uint32_t)__builtin_amdgcn_readlane((int)rm, 32);
        uint32_t m3 = (uint32_t)__builtin_amdgcn_readlane((int)rm, 48);
        uint32_t wm = m0 > m1 ? m0 : m1;
        uint32_t wmb = m2 > m3 ? m2 : m3;
        wm = wm > wmb ? wm : wmb;
        unsigned long long em = __ballot(vb == wm);
        uint32_t wi;
        if (__popcll(em) == 1) {
          wi = (uint32_t)__builtin_amdgcn_readlane(cmaxi, __ffsll(em) - 1);
        } else {
          uint32_t ik = (vb == wm) ? (uint32_t)cmaxi : 0xFFFFFFFFu;
          DPP_ROR_U32_MIN(ik)
          uint32_t i0 = (uint32_t)__builtin_amdgcn_readlane((int)ik, 0);
          uint32_t i1 = (uint32_t)__builtin_amdgcn_readlane((int)ik, 16);
          uint32_t i2 = (uint32_t)__builtin_amdgcn_readlane((int)ik, 32);
          uint32_t i3 = (uint32_t)__builtin_amdgcn_readlane((int)ik, 48);
          wi = i0 < i1 ? i0 : i1;
          uint32_t wib = i2 < i3 ? i2 : i3;
          wi = wi < wib ? wi : wib;
        }
        wwm = wm; wwi = wi;
      }

      const int buf = t & 1;
      if (lane == 0) { rec[buf][wv].x = wwm; rec[buf][wv].y = wwi; }
      __syncthreads();

      uint2 r = rec[buf][lane & 15];
      uint32_t bm = r.x;
      DPP_ROR_U32_MAX(bm)
      uint32_t ci = (r.x == bm) ? r.y : 0xFFFFFFFFu;
      DPP_ROR_U32_MIN(ci)
      int sidx = __builtin_amdgcn_readfirstlane((int)ci);

      cx = XL[3 * sidx + 0];
      cy = XL[3 * sidx + 1];
      cz = XL[3 * sidx + 2];

      if (tid == 0) {
        float* o = new_xyz + ((size_t)b * NPT + t) * 3;
        o[0] = cx; o[1] = cy; o[2] = cz;
        if ((t & 15) == 15)   // includes t=2047
          __hip_atomic_store(progress + b, t, __ATOMIC_RELEASE, __HIP_MEMORY_SCOPE_AGENT);
      }
    }
  } else {
    // ================= worker role: bq + group + MLP + pool =================
    float* G    = (float*)SM;                 // 67 x 128
    float* H1   = (float*)(SM + 34304);       // 128 x 128
    int*   lidx = (int*)(SM + 99840);         // 4 x 32
    float* ctr  = (float*)(SM + 100352);      // 4 x 3

    const int wbid = blockIdx.x - 4;          // 0..251

    for (int qg = wbid; qg < NQUAD; qg += NWORK) {
      const int b = qg & 3;                   // quads ordered by squad -> readiness-monotone
      const int s0 = (qg >> 2) * 4;           // first center (in-batch), 4 per quad
      const float* X  = xyz + (size_t)b * NPTS * 3;
      const float* Fp = FT + (size_t)b * NPTS * CIN;

      // 1) wait for fps to produce centers s0..s0+3
      if (tid == 0) {
        while (__hip_atomic_load(progress + b, __ATOMIC_ACQUIRE, __HIP_MEMORY_SCOPE_AGENT) < s0 + 3)
          __builtin_amdgcn_s_sleep(2);
      }
      __syncthreads();

      // 2) centers -> LDS; ball query: one wave per center (waves 0..3)
      if (tid < 12) ctr[tid] = new_xyz[((size_t)b * NPT + s0) * 3 + tid];
      if (wv < 4) {
        const int s = s0 + wv;
        const float cx = new_xyz[((size_t)b * NPT + s) * 3 + 0];
        const float cy = new_xyz[((size_t)b * NPT + s) * 3 + 1];
        const float cz = new_xyz[((size_t)b * NPT + s) * 3 + 2];
        int* out = lidx + wv * NS;
        int found = 0;
        int first = -1;
        for (int base = 0; base < NPTS; base += 64) {
          const int p = base + lane;
          float x = X[p * 3 + 0], y = X[p * 3 + 1], z = X[p * 3 + 2];
          float dx = x - cx, dy = y - cy, dz = z - cz;
          float d2 = __fadd_rn(__fadd_rn(__fmul_rn(dx, dx), __fmul_rn(dy, dy)), __fmul_rn(dz, dz));
          unsigned long long mask = __ballot(d2 < R2);
          if (mask != 0ull && first < 0) first = base + __ffsll((unsigned long long)mask) - 1;
          if (found < NS) {
            if ((mask >> lane) & 1ull) {
              int rank = found + __popcll(mask & ((1ull << lane) - 1ull));
              if (rank < NS) out[rank] = p;
            }
          }
          found += __popcll(mask);
          if (found >= NS) break;
        }
        if (found < NS) {
          int pad = (first < 0) ? 0 : first;
          if (lane >= found && lane < NS) out[lane] = pad;
        }
      }
      __syncthreads();

      // 3) G fill: feature rows via point-major FT (coalesced), rel-xyz rows
      {
        int j = tid >> 3, q = tid & 7;       // 128 points x 8 chunks
        int p = lidx[j];
        const float4* row = (const float4*)(Fp + (size_t)p * CIN);
        float4 v0 = row[q * 2 + 0];
        float4 v1 = row[q * 2 + 1];
        float vs[8] = {v0.x, v0.y, v0.z, v0.w, v1.x, v1.y, v1.z, v1.w};
#pragma unroll
        for (int i = 0; i < 8; ++i)
          G[(3 + q * 8 + i) * 128 + j] = vs[i];
      }
      if (tid < 384) {
        int c = tid >> 7, j = tid & 127;
        int p = lidx[j];
        G[c * 128 + j] = X[p * 3 + c] - ctr[(j >> 5) * 3 + c];
      }
      __syncthreads();

      // 4) H1 = relu(W1 @ G + b1): 128 x 128, each thread 4o x 4j
      {
        const int oi = tid >> 5, ji = tid & 31;
        const int o0 = oi * 4, j0 = ji * 4;
        float acc[4][4];
#pragma unroll
        for (int i = 0; i < 4; ++i)
#pragma unroll
          for (int jj = 0; jj < 4; ++jj) acc[i][jj] = 0.f;
#pragma unroll 4
        for (int c = 0; c < 67; ++c) {
          float4 g  = *(const float4*)&G[c * 128 + j0];
          float4 wf = *(const float4*)&w1t[c * 128 + o0];
          float ga[4] = {g.x, g.y, g.z, g.w};
          float wa[4] = {wf.x, wf.y, wf.z, wf.w};
#pragma unroll
          for (int i = 0; i < 4; ++i)
#pragma unroll
            for (int jj = 0; jj < 4; ++jj)
              acc[i][jj] = fmaf(wa[i], ga[jj], acc[i][jj]);
        }
        float4 bb = *(const float4*)&b1[o0];
        float ba[4] = {bb.x, bb.y, bb.z, bb.w};
#pragma unroll
        for (int i = 0; i < 4; ++i) {
          float4 h;
          h.x = fmaxf(acc[i][0] + ba[i], 0.f);
          h.y = fmaxf(acc[i][1] + ba[i], 0.f);
          h.z = fmaxf(acc[i][2] + ba[i], 0.f);
          h.w = fmaxf(acc[i][3] + ba[i], 0.f);
          *(float4*)&H1[(o0 + i) * 128 + j0] = h;
        }
      }
      __syncthreads();

      // 5) H2 = relu(W2 @ H1 + b2): 256 x 128, thread 8o x 4j, then maxpool
      {
        const int oi = tid >> 5, ji = tid & 31;
        const int o0 = oi * 8, j0 = ji * 4;
        float acc[8][4];
#pragma unroll
        for (int i = 0; i < 8; ++i)
#pragma unroll
          for (int jj = 0; jj < 4; ++jj) acc[i][jj] = 0.f;
#pragma unroll 2
        for (int c = 0; c < 128; ++c) {
          float4 h  = *(const float4*)&H1[c * 128 + j0];
          float4 wa4 = *(const float4*)&w2t[c * 256 + o0];
          float4 wb4 = *(const float4*)&w2t[c * 256 + o0 + 4];
          float ha[4] = {h.x, h.y, h.z, h.w};
          float wa[8] = {wa4.x, wa4.y, wa4.z, wa4.w, wb4.x, wb4.y, wb4.z, wb4.w};
#pragma unroll
          for (int i = 0; i < 8; ++i)
#pragma unroll
            for (int jj = 0; jj < 4; ++jj)
              acc[i][jj] = fmaf(wa[i], ha[jj], acc[i][jj]);
        }
        float4 b2a = *(const float4*)&b2[o0];
        float4 b2b = *(const float4*)&b2[o0 + 4];
        float bb[8] = {b2a.x, b2a.y, b2a.z, b2a.w, b2b.x, b2b.y, b2b.z, b2b.w};
        float m[8];
#pragma unroll
        for (int i = 0; i < 8; ++i) {
          float v0 = fmaxf(acc[i][0] + bb[i], 0.f);
          float v1 = fmaxf(acc[i][1] + bb[i], 0.f);
          float v2 = fmaxf(acc[i][2] + bb[i], 0.f);
          float v3 = fmaxf(acc[i][3] + bb[i], 0.f);
          m[i] = fmaxf(fmaxf(v0, v1), fmaxf(v2, v3));
        }
        // ji&7 groups (8 lanes x 4 j = 32 samples = one center); xor 1,2,4
        // stays within each 8-lane group.
#pragma unroll
        for (int off = 1; off < 8; off <<= 1)
#pragma unroll
          for (int i = 0; i < 8; ++i) m[i] = fmaxf(m[i], __shfl_xor(m[i], off));
        if ((ji & 7) == 0) {
          int sidx = s0 + (ji >> 3);
#pragma unroll
          for (int i = 0; i < 8; ++i)
            pooled[((size_t)b * 256 + o0 + i) * (size_t)NPT + sidx] = m[i];
        }
      }
    }
  }
}

extern "C" void kernel_launch(void* const* d_in, const int* in_sizes, int n_in,
                              void* d_out, int out_size, void* d_ws, size_t ws_size,
                              hipStream_t stream) {
  (void)in_sizes; (void)n_in; (void)out_size; (void)ws_size;
  const float* xyz  = (const float*)d_in[0];   // (4,8192,3)
  const float* feat = (const float*)d_in[1];   // (4,64,8192)
  const float* w1   = (const float*)d_in[2];   // (128,67)
  const float* b1   = (const float*)d_in[3];   // (128)
  const float* w2   = (const float*)d_in[4];   // (256,128)
  const float* b2   = (const float*)d_in[5];   // (256)

  float* out     = (float*)d_out;
  float* new_xyz = out;                        // (4,2048,3)
  float* pooled  = out + (size_t)BATCH * NPT * 3;  // (4,256,2048)

  char* ws = (char*)d_ws;
  float*  w1t      = (float*)ws;                       // 34304 B
  float*  w2t      = (float*)(ws + 34304);             // 131072 B -> 165376
  float4* sorted   = (float4*)(ws + 165376);           // 524288 B -> 689664
  float*  FT       = (float*)(ws + 689664);            // 8388608 B -> 9078272
  int*    progress = (int*)(ws + 9078272);             // 16 B

  prep_kernel<<<128, 256, 0, stream>>>(w1, w2, w1t, w2t);
  prep_t_kernel<<<BATCH * 128, 256, 0, stream>>>(feat, FT);
  sort_kernel<<<BATCH, 1024, 0, stream>>>(xyz, sorted);
  (void)hipMemsetAsync(progress, 0, 16, stream);
  fused_kernel<<<256, 1024, 0, stream>>>(xyz, sorted, FT, w1t, b1, w2t, b2,
                                         new_xyz, pooled, progress);
}

// Round 3
// 1896.163 us; speedup vs baseline: 1.3488x; 1.0316x over previous
//
#include <hip/hip_runtime.h>

// Problem constants (from reference)
#define NPTS   8192   // N
#define NPT    2048   // NPOINT
#define NS     32     // NSAMPLE
#define CIN    64
#define BATCH  4
// threshold: f32 nearest to 0.64 (numpy/jax weak-type the python float 0.8**2 to f32)
#define R2     0.64f

#define NWORK  252    // worker blocks (grid 256 = 4 fps + 252 workers = #CUs)
#define NQUAD  2048   // 8192 centers / 4 per quad

// ---------------- prep: transpose weights into ws ----------------
__global__ __launch_bounds__(256) void prep_kernel(const float* __restrict__ w1,
                                                   const float* __restrict__ w2,
                                                   float* __restrict__ w1t,
                                                   float* __restrict__ w2t) {
  int i = blockIdx.x * 256 + threadIdx.x;
  if (i < 128 * 67) {
    int o = i / 67, c = i % 67;
    w1t[c * 128 + o] = w1[i];
  }
  if (i < 256 * 128) {
    int o = i >> 7, c = i & 127;
    w2t[c * 256 + o] = w2[i];
  }
}

// ---------------- prep_t: transpose feat (B,C,N) -> FT (B,N,C) ----------------
__global__ __launch_bounds__(256) void prep_t_kernel(const float* __restrict__ feat,
                                                     float* __restrict__ FT) {
  const int b = blockIdx.x >> 7;
  const int n0 = (blockIdx.x & 127) << 6;
  const int tid = threadIdx.x;
  __shared__ float T[64][65];

  const float* F = feat + (size_t)b * CIN * NPTS;
#pragma unroll
  for (int p = 0; p < 16; ++p) {
    int c = p * 4 + (tid >> 6), ln = tid & 63;
    T[c][ln] = F[(size_t)c * NPTS + n0 + ln];
  }
  __syncthreads();
  float* O = FT + (size_t)b * NPTS * CIN;
#pragma unroll
  for (int p = 0; p < 4; ++p) {
    int j = tid >> 2, q = (tid & 3) + p * 4;
    float4 v = make_float4(T[q * 4 + 0][j], T[q * 4 + 1][j],
                           T[q * 4 + 2][j], T[q * 4 + 3][j]);
    *(float4*)&O[(size_t)(n0 + j) * CIN + q * 4] = v;
  }
}

// ---------------- Morton sort (u32 keys, in-LDS bitonic) ----------------
__device__ inline uint32_t part1by2(uint32_t x) {
  x &= 1023u;
  x = (x | (x << 16)) & 0x030000FFu;
  x = (x | (x << 8))  & 0x0300F00Fu;
  x = (x | (x << 4))  & 0x030C30C3u;
  x = (x | (x << 2))  & 0x09249249u;
  return x;
}

__device__ inline uint32_t morton3(float x, float y, float z) {
  int qx = (int)((x + 16.f) * 32.f);
  int qy = (int)((y + 16.f) * 32.f);
  int qz = (int)((z + 16.f) * 32.f);
  qx = qx < 0 ? 0 : (qx > 1023 ? 1023 : qx);
  qy = qy < 0 ? 0 : (qy > 1023 ? 1023 : qy);
  qz = qz < 0 ? 0 : (qz > 1023 ? 1023 : qz);
  return part1by2((uint32_t)qx) | (part1by2((uint32_t)qy) << 1) | (part1by2((uint32_t)qz) << 2);
}

__global__ __launch_bounds__(1024) void sort_kernel(const float* __restrict__ xyz,
                                                    float4* __restrict__ sorted) {
  const int b = blockIdx.x;
  const int tid = threadIdx.x;
  const float* X = xyz + (size_t)b * NPTS * 3;
  __shared__ uint32_t S[NPTS];  // 32 KB

  for (int k = 0; k < 8; ++k) {
    int p = tid + (k << 10);
    uint32_t m = morton3(X[p * 3 + 0], X[p * 3 + 1], X[p * 3 + 2]);
    S[p] = ((m >> 11) << 13) | (uint32_t)p;
  }
  __syncthreads();
  for (unsigned k = 2; k <= NPTS; k <<= 1) {
    for (unsigned j = k >> 1; j > 0; j >>= 1) {
      for (int i = tid; i < NPTS; i += 1024) {
        int l = i ^ (int)j;
        if (l > i) {
          uint32_t a = S[i], c = S[l];
          bool sw = ((i & k) == 0) ? (a > c) : (a < c);
          if (sw) { S[i] = c; S[l] = a; }
        }
      }
      __syncthreads();
    }
  }
  for (int k = 0; k < 8; ++k) {
    int pos = tid + (k << 10);
    int o = (int)(S[pos] & 8191u);
    float4 v;
    v.x = X[o * 3 + 0]; v.y = X[o * 3 + 1]; v.z = X[o * 3 + 2];
    v.w = __int_as_float(o);
    sorted[(size_t)b * NPTS + pos] = v;
  }
}

// ---------------- fused FPS + (ballquery + group + MLP + pool) workers --------
// Blocks 0..3: FPS. Selection math is the verified scalar R7/R10 body
//   (bit-exact). R2 change: the winner's COORDINATES travel through the
//   cross-wave record (recc) instead of a dependent XL[3*sidx] LDS read at
//   the end of each iteration:
//   - active lanes track their argmax point's coords with the SAME predicate
//     as the argmax index (3 cndmask per point, active lanes only);
//   - pruned lanes' (cmaxv, cmaxi, coords) triple is exactly consistent
//     (the prune guarantees no dmin of theirs changed);
//   - winner lane identified by the existing em ballot (em2 on value ties);
//     3 readlanes -> uniform coords; lane0 stores (wm,wi)+float4 coords;
//   - post-barrier: rec+recc reads overlap, DPP-max, ballot+ffs fast path
//     (DPP-min only on cross-wave value ties), 3 readlanes -> center.
//   Coords are bit-copies of X either way -> bit-identical output.
//   The 96 KB XL table and its fill are gone. Serial tail ~340 -> ~200 cyc.
// Blocks 4..255: persistent workers; unchanged.

#define DPP_ROR_U32_MAX(v)                                                       \
  {                                                                              \
    uint32_t _t;                                                                 \
    _t = (uint32_t)__builtin_amdgcn_update_dpp(0, (int)(v), 0x121, 0xF, 0xF, false); if (_t > (v)) (v) = _t; \
    _t = (uint32_t)__builtin_amdgcn_update_dpp(0, (int)(v), 0x122, 0xF, 0xF, false); if (_t > (v)) (v) = _t; \
    _t = (uint32_t)__builtin_amdgcn_update_dpp(0, (int)(v), 0x124, 0xF, 0xF, false); if (_t > (v)) (v) = _t; \
    _t = (uint32_t)__builtin_amdgcn_update_dpp(0, (int)(v), 0x128, 0xF, 0xF, false); if (_t > (v)) (v) = _t; \
  }

#define DPP_ROR_U32_MIN(v)                                                       \
  {                                                                              \
    uint32_t _t;                                                                 \
    _t = (uint32_t)__builtin_amdgcn_update_dpp(-1, (int)(v), 0x121, 0xF, 0xF, false); if (_t < (v)) (v) = _t; \
    _t = (uint32_t)__builtin_amdgcn_update_dpp(-1, (int)(v), 0x122, 0xF, 0xF, false); if (_t < (v)) (v) = _t; \
    _t = (uint32_t)__builtin_amdgcn_update_dpp(-1, (int)(v), 0x124, 0xF, 0xF, false); if (_t < (v)) (v) = _t; \
    _t = (uint32_t)__builtin_amdgcn_update_dpp(-1, (int)(v), 0x128, 0xF, 0xF, false); if (_t < (v)) (v) = _t; \
  }

#define CSWAP(i, j)                                                              \
  if (oid[i] > oid[j]) {                                                         \
    int _ti = oid[i]; oid[i] = oid[j]; oid[j] = _ti;                             \
    float _tf;                                                                   \
    _tf = px[i]; px[i] = px[j]; px[j] = _tf;                                     \
    _tf = py[i]; py[i] = py[j]; py[j] = _tf;                                     \
    _tf = pz[i]; pz[i] = pz[j]; pz[j] = _tf;                                     \
  }

__global__ __launch_bounds__(1024, 1) void fused_kernel(
    const float* __restrict__ xyz, const float4* __restrict__ sorted,
    const float* __restrict__ FT,
    const float* __restrict__ w1t, const float* __restrict__ b1,
    const float* __restrict__ w2t, const float* __restrict__ b2,
    float* __restrict__ new_xyz, float* __restrict__ pooled,
    int* __restrict__ progress) {
  const int tid = threadIdx.x;
  const int lane = tid & 63;
  const int wv = tid >> 6;

  __shared__ __align__(16) char SM[100416];   // ~100 KB -> 1 block/CU

  if (blockIdx.x < 4) {
    // ================= FPS role =================
    const int b = blockIdx.x;
    uint2  (*rec)[16]  = (uint2(*)[16])(SM + 98304);    // [2][16] (wm, wi)
    float4 (*recc)[16] = (float4(*)[16])(SM + 98560);   // [2][16] winner coords
    const float* X = xyz + (size_t)b * NPTS * 3;
    const float4* SP = sorted + (size_t)b * NPTS;

    float px[8], py[8], pz[8], dmin[8];
    int oid[8];
#pragma unroll
    for (int k = 0; k < 8; ++k) {
      float4 p = SP[tid * 8 + k];
      px[k] = p.x; py[k] = p.y; pz[k] = p.z;
      oid[k] = __float_as_int(p.w);
      dmin[k] = 1e10f;
    }
    CSWAP(0, 1) CSWAP(2, 3) CSWAP(4, 5) CSWAP(6, 7)
    CSWAP(0, 2) CSWAP(1, 3) CSWAP(4, 6) CSWAP(5, 7)
    CSWAP(1, 2) CSWAP(5, 6)
    CSWAP(0, 4) CSWAP(1, 5) CSWAP(2, 6) CSWAP(3, 7)
    CSWAP(2, 4) CSWAP(3, 5)
    CSWAP(1, 2) CSWAP(3, 4) CSWAP(5, 6)

    float bxmin = px[0], bxmax = px[0], bymin = py[0], bymax = py[0], bzmin = pz[0], bzmax = pz[0];
#pragma unroll
    for (int k = 1; k < 8; ++k) {
      bxmin = fminf(bxmin, px[k]); bxmax = fmaxf(bxmax, px[k]);
      bymin = fminf(bymin, py[k]); bymax = fmaxf(bymax, py[k]);
      bzmin = fminf(bzmin, pz[k]); bzmax = fmaxf(bzmax, pz[k]);
    }

    float cmaxv = 1e10f;
    int   cmaxi = oid[0];
    float cwx = px[0], cwy = py[0], cwz = pz[0];   // coords of cmaxi's point
    uint32_t wwm = 0u, wwi = 0u;
    float wwx = 0.f, wwy = 0.f, wwz = 0.f;

    float cx = X[0], cy = X[1], cz = X[2];
    if (tid == 0) {
      new_xyz[(size_t)b * NPT * 3 + 0] = cx;
      new_xyz[(size_t)b * NPT * 3 + 1] = cy;
      new_xyz[(size_t)b * NPT * 3 + 2] = cz;
    }

    for (int t = 1; t < NPT; ++t) {
      float ex = fmaxf(fmaxf(bxmin - cx, cx - bxmax), 0.f);
      float ey = fmaxf(fmaxf(bymin - cy, cy - bymax), 0.f);
      float ez = fmaxf(fmaxf(bzmin - cz, cz - bzmax), 0.f);
      float dlb = (ex * ex + ey * ey + ez * ez) * 0.9999f;
      bool act = dlb < cmaxv;

      if (__ballot(act)) {
        if (act) {
          float mv = -1.0f; int mi = 0;
          float mx = px[0], my = py[0], mz = pz[0];
#pragma unroll
          for (int k = 0; k < 8; ++k) {
            float dx = px[k] - cx, dy = py[k] - cy, dz = pz[k] - cz;
            float d = __fadd_rn(__fadd_rn(__fmul_rn(dx, dx), __fmul_rn(dy, dy)), __fmul_rn(dz, dz));
            float dm = fminf(dmin[k], d);
            dmin[k] = dm;
            if (dm > mv) { mv = dm; mi = oid[k]; mx = px[k]; my = py[k]; mz = pz[k]; }
          }
          cmaxv = mv; cmaxi = mi; cwx = mx; cwy = my; cwz = mz;
        }
        uint32_t vb = __float_as_uint(cmaxv);
        uint32_t rm = vb;
        DPP_ROR_U32_MAX(rm)
        uint32_t m0 = (uint32_t)__builtin_amdgcn_readlane((int)rm, 0);
        uint32_t m1 = (uint32_t)__builtin_amdgcn_readlane((int)rm, 16);
        uint32_t m2 = (uint32_t)__builtin_amdgcn_readlane((int)rm, 32);
        uint32_t m3 = (uint32_t)__builtin_amdgcn_readlane((int)rm, 48);
        uint32_t wm = m0 > m1 ? m0 : m1;
        uint32_t wmb = m2 > m3 ? m2 : m3;
        wm = wm > wmb ? wm : wmb;
        unsigned long long em = __ballot(vb == wm);
        uint32_t wi;
        int l;
        if (__popcll(em) == 1) {
          l = __ffsll(em) - 1;
          wi = (uint32_t)__builtin_amdgcn_readlane(cmaxi, l);
        } else {
          uint32_t ik = (vb == wm) ? (uint32_t)cmaxi : 0xFFFFFFFFu;
          DPP_ROR_U32_MIN(ik)
          uint32_t i0 = (uint32_t)__builtin_amdgcn_readlane((int)ik, 0);
          uint32_t i1 = (uint32_t)__builtin_amdgcn_readlane((int)ik, 16);
          uint32_t i2 = (uint32_t)__builtin_amdgcn_readlane((int)ik, 32);
          uint32_t i3 = (uint32_t)__builtin_amdgcn_readlane((int)ik, 48);
          wi = i0 < i1 ? i0 : i1;
          uint32_t wib = i2 < i3 ? i2 : i3;
          wi = wi < wib ? wi : wib;
          unsigned long long em2 = __ballot(vb == wm && (uint32_t)cmaxi == wi);
          l = __ffsll(em2) - 1;
        }
        wwm = wm; wwi = wi;
        // winner lane l holds point wi's coords (triple kept consistent even
        // when the lane was pruned this iteration)
        wwx = __int_as_float(__builtin_amdgcn_readlane(__float_as_int(cwx), l));
        wwy = __int_as_float(__builtin_amdgcn_readlane(__float_as_int(cwy), l));
        wwz = __int_as_float(__builtin_amdgcn_readlane(__float_as_int(cwz), l));
      }

      const int buf = t & 1;
      if (lane == 0) {
        rec[buf][wv].x = wwm; rec[buf][wv].y = wwi;
        recc[buf][wv] = make_float4(wwx, wwy, wwz, 0.f);
      }
      __syncthreads();

      uint2  r  = rec[buf][lane & 15];
      float4 rc = recc[buf][lane & 15];
      uint32_t bm = r.x;
      DPP_ROR_U32_MAX(bm)
      // rows 0-3 hold identical data -> bm is uniform across the wave
      unsigned em16 = (unsigned)(__ballot(r.x == bm) & 0xFFFFull);
      int w;
      if (__popc(em16) == 1) {
        w = __ffs(em16) - 1;
      } else {
        uint32_t ci = (r.x == bm) ? r.y : 0xFFFFFFFFu;
        DPP_ROR_U32_MIN(ci)
        uint32_t wig = (uint32_t)__builtin_amdgcn_readfirstlane((int)ci);
        unsigned e2 = (unsigned)(__ballot(r.x == bm && r.y == wig) & 0xFFFFull);
        w = __ffs(e2) - 1;
      }
      cx = __int_as_float(__builtin_amdgcn_readlane(__float_as_int(rc.x), w));
      cy = __int_as_float(__builtin_amdgcn_readlane(__float_as_int(rc.y), w));
      cz = __int_as_float(__builtin_amdgcn_readlane(__float_as_int(rc.z), w));

      if (tid == 0) {
        float* o = new_xyz + ((size_t)b * NPT + t) * 3;
        o[0] = cx; o[1] = cy; o[2] = cz;
        if ((t & 15) == 15)   // includes t=2047
          __hip_atomic_store(progress + b, t, __ATOMIC_RELEASE, __HIP_MEMORY_SCOPE_AGENT);
      }
    }
  } else {
    // ================= worker role: bq + group + MLP + pool =================
    float* G    = (float*)SM;                 // 67 x 128
    float* H1   = (float*)(SM + 34304);       // 128 x 128
    int*   lidx = (int*)(SM + 99840);         // 4 x 32
    float* ctr  = (float*)(SM + 100352);      // 4 x 3

    const int wbid = blockIdx.x - 4;          // 0..251

    for (int qg = wbid; qg < NQUAD; qg += NWORK) {
      const int b = qg & 3;                   // quads ordered by squad -> readiness-monotone
      const int s0 = (qg >> 2) * 4;           // first center (in-batch), 4 per quad
      const float* X  = xyz + (size_t)b * NPTS * 3;
      const float* Fp = FT + (size_t)b * NPTS * CIN;

      // 1) wait for fps to produce centers s0..s0+3
      if (tid == 0) {
        while (__hip_atomic_load(progress + b, __ATOMIC_ACQUIRE, __HIP_MEMORY_SCOPE_AGENT) < s0 + 3)
          __builtin_amdgcn_s_sleep(2);
      }
      __syncthreads();

      // 2) centers -> LDS; ball query: one wave per center (waves 0..3)
      if (tid < 12) ctr[tid] = new_xyz[((size_t)b * NPT + s0) * 3 + tid];
      if (wv < 4) {
        const int s = s0 + wv;
        const float cx = new_xyz[((size_t)b * NPT + s) * 3 + 0];
        const float cy = new_xyz[((size_t)b * NPT + s) * 3 + 1];
        const float cz = new_xyz[((size_t)b * NPT + s) * 3 + 2];
        int* out = lidx + wv * NS;
        int found = 0;
        int first = -1;
        for (int base = 0; base < NPTS; base += 64) {
          const int p = base + lane;
          float x = X[p * 3 + 0], y = X[p * 3 + 1], z = X[p * 3 + 2];
          float dx = x - cx, dy = y - cy, dz = z - cz;
          float d2 = __fadd_rn(__fadd_rn(__fmul_rn(dx, dx), __fmul_rn(dy, dy)), __fmul_rn(dz, dz));
          unsigned long long mask = __ballot(d2 < R2);
          if (mask != 0ull && first < 0) first = base + __ffsll((unsigned long long)mask) - 1;
          if (found < NS) {
            if ((mask >> lane) & 1ull) {
              int rank = found + __popcll(mask & ((1ull << lane) - 1ull));
              if (rank < NS) out[rank] = p;
            }
          }
          found += __popcll(mask);
          if (found >= NS) break;
        }
        if (found < NS) {
          int pad = (first < 0) ? 0 : first;
          if (lane >= found && lane < NS) out[lane] = pad;
        }
      }
      __syncthreads();

      // 3) G fill: feature rows via point-major FT (coalesced), rel-xyz rows
      {
        int j = tid >> 3, q = tid & 7;       // 128 points x 8 chunks
        int p = lidx[j];
        const float4* row = (const float4*)(Fp + (size_t)p * CIN);
        float4 v0 = row[q * 2 + 0];
        float4 v1 = row[q * 2 + 1];
        float vs[8] = {v0.x, v0.y, v0.z, v0.w, v1.x, v1.y, v1.z, v1.w};
#pragma unroll
        for (int i = 0; i < 8; ++i)
          G[(3 + q * 8 + i) * 128 + j] = vs[i];
      }
      if (tid < 384) {
        int c = tid >> 7, j = tid & 127;
        int p = lidx[j];
        G[c * 128 + j] = X[p * 3 + c] - ctr[(j >> 5) * 3 + c];
      }
      __syncthreads();

      // 4) H1 = relu(W1 @ G + b1): 128 x 128, each thread 4o x 4j
      {
        const int oi = tid >> 5, ji = tid & 31;
        const int o0 = oi * 4, j0 = ji * 4;
        float acc[4][4];
#pragma unroll
        for (int i = 0; i < 4; ++i)
#pragma unroll
          for (int jj = 0; jj < 4; ++jj) acc[i][jj] = 0.f;
#pragma unroll 4
        for (int c = 0; c < 67; ++c) {
          float4 g  = *(const float4*)&G[c * 128 + j0];
          float4 wf = *(const float4*)&w1t[c * 128 + o0];
          float ga[4] = {g.x, g.y, g.z, g.w};
          float wa[4] = {wf.x, wf.y, wf.z, wf.w};
#pragma unroll
          for (int i = 0; i < 4; ++i)
#pragma unroll
            for (int jj = 0; jj < 4; ++jj)
              acc[i][jj] = fmaf(wa[i], ga[jj], acc[i][jj]);
        }
        float4 bb = *(const float4*)&b1[o0];
        float ba[4] = {bb.x, bb.y, bb.z, bb.w};
#pragma unroll
        for (int i = 0; i < 4; ++i) {
          float4 h;
          h.x = fmaxf(acc[i][0] + ba[i], 0.f);
          h.y = fmaxf(acc[i][1] + ba[i], 0.f);
          h.z = fmaxf(acc[i][2] + ba[i], 0.f);
          h.w = fmaxf(acc[i][3] + ba[i], 0.f);
          *(float4*)&H1[(o0 + i) * 128 + j0] = h;
        }
      }
      __syncthreads();

      // 5) H2 = relu(W2 @ H1 + b2): 256 x 128, thread 8o x 4j, then maxpool
      {
        const int oi = tid >> 5, ji = tid & 31;
        const int o0 = oi * 8, j0 = ji * 4;
        float acc[8][4];
#pragma unroll
        for (int i = 0; i < 8; ++i)
#pragma unroll
          for (int jj = 0; jj < 4; ++jj) acc[i][jj] = 0.f;
#pragma unroll 2
        for (int c = 0; c < 128; ++c) {
          float4 h  = *(const float4*)&H1[c * 128 + j0];
          float4 wa4 = *(const float4*)&w2t[c * 256 + o0];
          float4 wb4 = *(const float4*)&w2t[c * 256 + o0 + 4];
          float ha[4] = {h.x, h.y, h.z, h.w};
          float wa[8] = {wa4.x, wa4.y, wa4.z, wa4.w, wb4.x, wb4.y, wb4.z, wb4.w};
#pragma unroll
          for (int i = 0; i < 8; ++i)
#pragma unroll
            for (int jj = 0; jj < 4; ++jj)
              acc[i][jj] = fmaf(wa[i], ha[jj], acc[i][jj]);
        }
        float4 b2a = *(const float4*)&b2[o0];
        float4 b2b = *(const float4*)&b2[o0 + 4];
        float bb[8] = {b2a.x, b2a.y, b2a.z, b2a.w, b2b.x, b2b.y, b2b.z, b2b.w};
        float m[8];
#pragma unroll
        for (int i = 0; i < 8; ++i) {
          float v0 = fmaxf(acc[i][0] + bb[i], 0.f);
          float v1 = fmaxf(acc[i][1] + bb[i], 0.f);
          float v2 = fmaxf(acc[i][2] + bb[i], 0.f);
          float v3 = fmaxf(acc[i][3] + bb[i], 0.f);
          m[i] = fmaxf(fmaxf(v0, v1), fmaxf(v2, v3));
        }
        // ji&7 groups (8 lanes x 4 j = 32 samples = one center); xor 1,2,4
        // stays within each 8-lane group.
#pragma unroll
        for (int off = 1; off < 8; off <<= 1)
#pragma unroll
          for (int i = 0; i < 8; ++i) m[i] = fmaxf(m[i], __shfl_xor(m[i], off));
        if ((ji & 7) == 0) {
          int sidx = s0 + (ji >> 3);
#pragma unroll
          for (int i = 0; i < 8; ++i)
            pooled[((size_t)b * 256 + o0 + i) * (size_t)NPT + sidx] = m[i];
        }
      }
    }
  }
}

extern "C" void kernel_launch(void* const* d_in, const int* in_sizes, int n_in,
                              void* d_out, int out_size, void* d_ws, size_t ws_size,
                              hipStream_t stream) {
  (void)in_sizes; (void)n_in; (void)out_size; (void)ws_size;
  const float* xyz  = (const float*)d_in[0];   // (4,8192,3)
  const float* feat = (const float*)d_in[1];   // (4,64,8192)
  const float* w1   = (const float*)d_in[2];   // (128,67)
  const float* b1   = (const float*)d_in[3];   // (128)
  const float* w2   = (const float*)d_in[4];   // (256,128)
  const float* b2   = (const float*)d_in[5];   // (256)

  float* out     = (float*)d_out;
  float* new_xyz = out;                        // (4,2048,3)
  float* pooled  = out + (size_t)BATCH * NPT * 3;  // (4,256,2048)

  char* ws = (char*)d_ws;
  float*  w1t      = (float*)ws;                       // 34304 B
  float*  w2t      = (float*)(ws + 34304);             // 131072 B -> 165376
  float4* sorted   = (float4*)(ws + 165376);           // 524288 B -> 689664
  float*  FT       = (float*)(ws + 689664);            // 8388608 B -> 9078272
  int*    progress = (int*)(ws + 9078272);             // 16 B

  prep_kernel<<<128, 256, 0, stream>>>(w1, w2, w1t, w2t);
  prep_t_kernel<<<BATCH * 128, 256, 0, stream>>>(feat, FT);
  sort_kernel<<<BATCH, 1024, 0, stream>>>(xyz, sorted);
  (void)hipMemsetAsync(progress, 0, 16, stream);
  fused_kernel<<<256, 1024, 0, stream>>>(xyz, sorted, FT, w1t, b1, w2t, b2,
                                         new_xyz, pooled, progress);
}

// Round 4
// 1703.753 us; speedup vs baseline: 1.5011x; 1.1129x over previous
//
#include <hip/hip_runtime.h>

// Problem constants (from reference)
#define NPTS   8192   // N
#define NPT    2048   // NPOINT
#define NS     32     // NSAMPLE
#define CIN    64
#define BATCH  4
// threshold: f32 nearest to 0.64 (numpy/jax weak-type the python float 0.8**2 to f32)
#define R2     0.64f

#define NWORK  252    // worker blocks (grid 256 = 4 fps + 252 workers = #CUs)
#define NQUAD  2048   // 8192 centers / 4 per quad

// ---------------- Morton helpers ----------------
__device__ inline uint32_t part1by2(uint32_t x) {
  x &= 1023u;
  x = (x | (x << 16)) & 0x030000FFu;
  x = (x | (x << 8))  & 0x0300F00Fu;
  x = (x | (x << 4))  & 0x030C30C3u;
  x = (x | (x << 2))  & 0x09249249u;
  return x;
}

__device__ inline uint32_t morton3(float x, float y, float z) {
  int qx = (int)((x + 16.f) * 32.f);
  int qy = (int)((y + 16.f) * 32.f);
  int qz = (int)((z + 16.f) * 32.f);
  qx = qx < 0 ? 0 : (qx > 1023 ? 1023 : qx);
  qy = qy < 0 ? 0 : (qy > 1023 ? 1023 : qy);
  qz = qz < 0 ? 0 : (qz > 1023 ? 1023 : qz);
  return part1by2((uint32_t)qx) | (part1by2((uint32_t)qy) << 1) | (part1by2((uint32_t)qz) << 2);
}

// ---------------- single fused kernel --------------------------------------
// R3 design (post-mortem of R0-R2: FPS body is issue-bound with ~all waves
// active; DON'T touch the verified body. Attack surrounding overheads):
//  (a) center-store batching: per-iter tid0 global stores forced a
//      s_waitcnt vmcnt(0) drain at every __syncthreads (wave 0 pays L2
//      store-ack ~200-400cy/iter, all waves wait). Now: 3 ds_writes into a
//      48-float LDS ring per iter; every 16 iters flush 12 dwordx4 stores +
//      release-atomic progress. vmem drain amortized 16x. Workers only read
//      centers <= progress -> ordering preserved; bits unchanged.
//  (b) sort merged into FPS pre-phase: identical bitonic on identical keys
//      (computed from XL, a bit-copy of xyz) -> identical order; kills the
//      sort_kernel launch + 'sorted' global round-trip.
//  (c) prep/prep_t merged into worker pre-phase: 512 transpose tiles striped
//      over 252 blocks + weights by block 4; published via agent-scope
//      release counter (same verified pattern as progress/new_xyz); hidden
//      under FPS's sort phase.
// Blocks 0..3: FPS role (verified R7/R10 body, bit-exact). Blocks 4..255:
// persistent workers. 1 block/CU by LDS (>80KB), grid 256 = #CUs.

#define DPP_ROR_U32_MAX(v)                                                       \
  {                                                                              \
    uint32_t _t;                                                                 \
    _t = (uint32_t)__builtin_amdgcn_update_dpp(0, (int)(v), 0x121, 0xF, 0xF, false); if (_t > (v)) (v) = _t; \
    _t = (uint32_t)__builtin_amdgcn_update_dpp(0, (int)(v), 0x122, 0xF, 0xF, false); if (_t > (v)) (v) = _t; \
    _t = (uint32_t)__builtin_amdgcn_update_dpp(0, (int)(v), 0x124, 0xF, 0xF, false); if (_t > (v)) (v) = _t; \
    _t = (uint32_t)__builtin_amdgcn_update_dpp(0, (int)(v), 0x128, 0xF, 0xF, false); if (_t > (v)) (v) = _t; \
  }

#define DPP_ROR_U32_MIN(v)                                                       \
  {                                                                              \
    uint32_t _t;                                                                 \
    _t = (uint32_t)__builtin_amdgcn_update_dpp(-1, (int)(v), 0x121, 0xF, 0xF, false); if (_t < (v)) (v) = _t; \
    _t = (uint32_t)__builtin_amdgcn_update_dpp(-1, (int)(v), 0x122, 0xF, 0xF, false); if (_t < (v)) (v) = _t; \
    _t = (uint32_t)__builtin_amdgcn_update_dpp(-1, (int)(v), 0x124, 0xF, 0xF, false); if (_t < (v)) (v) = _t; \
    _t = (uint32_t)__builtin_amdgcn_update_dpp(-1, (int)(v), 0x128, 0xF, 0xF, false); if (_t < (v)) (v) = _t; \
  }

#define CSWAP(i, j)                                                              \
  if (oid[i] > oid[j]) {                                                         \
    int _ti = oid[i]; oid[i] = oid[j]; oid[j] = _ti;                             \
    float _tf;                                                                   \
    _tf = px[i]; px[i] = px[j]; px[j] = _tf;                                     \
    _tf = py[i]; py[i] = py[j]; py[j] = _tf;                                     \
    _tf = pz[i]; pz[i] = pz[j]; pz[j] = _tf;                                     \
  }

__global__ __launch_bounds__(1024, 1) void fused_kernel(
    const float* __restrict__ xyz, const float* __restrict__ feat,
    const float* __restrict__ w1, const float* __restrict__ b1,
    const float* __restrict__ w2, const float* __restrict__ b2,
    float* __restrict__ w1t, float* __restrict__ w2t,
    float* __restrict__ FT,
    float* __restrict__ new_xyz, float* __restrict__ pooled,
    int* __restrict__ progress) {
  const int tid = threadIdx.x;
  const int lane = tid & 63;
  const int wv = tid >> 6;
  int* ftflag = progress + 4;

  // XL 0..98304 | S 98304..131072 | rec 131072..131328 | ring 131328..131520
  __shared__ __align__(16) char SM[131520];

  if (blockIdx.x < 4) {
    // ================= FPS role =================
    const int b = blockIdx.x;
    float*     XL  = (float*)SM;                       // 96 KB coord table
    uint32_t*  S   = (uint32_t*)(SM + 98304);          // 32 KB sort keys
    uint2 (*rec)[16] = (uint2(*)[16])(SM + 131072);    // [2][16]
    float*     ring = (float*)(SM + 131328);           // 16 x 3 centers
    const float* X = xyz + (size_t)b * NPTS * 3;

    // ---- pre-phase: XL fill + Morton keys + bitonic sort (was sort_kernel)
    for (int i = tid; i < NPTS * 3; i += 1024) XL[i] = X[i];
    __syncthreads();
    for (int k = 0; k < 8; ++k) {
      int p = tid + (k << 10);
      uint32_t m = morton3(XL[p * 3 + 0], XL[p * 3 + 1], XL[p * 3 + 2]);
      S[p] = ((m >> 11) << 13) | (uint32_t)p;
    }
    __syncthreads();
    for (unsigned kk = 2; kk <= NPTS; kk <<= 1) {
      for (unsigned j = kk >> 1; j > 0; j >>= 1) {
        for (int i = tid; i < NPTS; i += 1024) {
          int l = i ^ (int)j;
          if (l > i) {
            uint32_t a = S[i], c = S[l];
            bool sw = ((i & kk) == 0) ? (a > c) : (a < c);
            if (sw) { S[i] = c; S[l] = a; }
          }
        }
        __syncthreads();
      }
    }

    // ---- per-thread registers from sorted order (bit-copies of X)
    float px[8], py[8], pz[8], dmin[8];
    int oid[8];
#pragma unroll
    for (int k = 0; k < 8; ++k) {
      int o = (int)(S[tid * 8 + k] & 8191u);
      px[k] = XL[3 * o + 0]; py[k] = XL[3 * o + 1]; pz[k] = XL[3 * o + 2];
      oid[k] = o;
      dmin[k] = 1e10f;
    }
    CSWAP(0, 1) CSWAP(2, 3) CSWAP(4, 5) CSWAP(6, 7)
    CSWAP(0, 2) CSWAP(1, 3) CSWAP(4, 6) CSWAP(5, 7)
    CSWAP(1, 2) CSWAP(5, 6)
    CSWAP(0, 4) CSWAP(1, 5) CSWAP(2, 6) CSWAP(3, 7)
    CSWAP(2, 4) CSWAP(3, 5)
    CSWAP(1, 2) CSWAP(3, 4) CSWAP(5, 6)

    float bxmin = px[0], bxmax = px[0], bymin = py[0], bymax = py[0], bzmin = pz[0], bzmax = pz[0];
#pragma unroll
    for (int k = 1; k < 8; ++k) {
      bxmin = fminf(bxmin, px[k]); bxmax = fmaxf(bxmax, px[k]);
      bymin = fminf(bymin, py[k]); bymax = fmaxf(bymax, py[k]);
      bzmin = fminf(bzmin, pz[k]); bzmax = fmaxf(bzmax, pz[k]);
    }
    float cmaxv = 1e10f;
    int   cmaxi = oid[0];
    uint32_t wwm = 0u, wwi = 0u;

    float cx = XL[0], cy = XL[1], cz = XL[2];
    if (tid == 0) { ring[0] = cx; ring[1] = cy; ring[2] = cz; }  // slot 0 = t0

    for (int t = 1; t < NPT; ++t) {
      float ex = fmaxf(fmaxf(bxmin - cx, cx - bxmax), 0.f);
      float ey = fmaxf(fmaxf(bymin - cy, cy - bymax), 0.f);
      float ez = fmaxf(fmaxf(bzmin - cz, cz - bzmax), 0.f);
      float dlb = (ex * ex + ey * ey + ez * ez) * 0.9999f;
      bool act = dlb < cmaxv;

      if (__ballot(act)) {
        if (act) {
          float mv = -1.0f; int mi = 0;
#pragma unroll
          for (int k = 0; k < 8; ++k) {
            float dx = px[k] - cx, dy = py[k] - cy, dz = pz[k] - cz;
            float d = __fadd_rn(__fadd_rn(__fmul_rn(dx, dx), __fmul_rn(dy, dy)), __fmul_rn(dz, dz));
            float dm = fminf(dmin[k], d);
            dmin[k] = dm;
            if (dm > mv) { mv = dm; mi = oid[k]; }
          }
          cmaxv = mv; cmaxi = mi;
        }
        uint32_t vb = __float_as_uint(cmaxv);
        uint32_t rm = vb;
        DPP_ROR_U32_MAX(rm)
        uint32_t m0 = (uint32_t)__builtin_amdgcn_readlane((int)rm, 0);
        uint32_t m1 = (uint32_t)__builtin_amdgcn_readlane((int)rm, 16);
        uint32_t m2 = (uint32_t)__builtin_amdgcn_readlane((int)rm, 32);
        uint32_t m3 = (uint32_t)__builtin_amdgcn_readlane((int)rm, 48);
        uint32_t wm = m0 > m1 ? m0 : m1;
        uint32_t wmb = m2 > m3 ? m2 : m3;
        wm = wm > wmb ? wm : wmb;
        unsigned long long em = __ballot(vb == wm);
        uint32_t wi;
        if (__popcll(em) == 1) {
          wi = (uint32_t)__builtin_amdgcn_readlane(cmaxi, __ffsll(em) - 1);
        } else {
          uint32_t ik = (vb == wm) ? (uint32_t)cmaxi : 0xFFFFFFFFu;
          DPP_ROR_U32_MIN(ik)
          uint32_t i0 = (uint32_t)__builtin_amdgcn_readlane((int)ik, 0);
          uint32_t i1 = (uint32_t)__builtin_amdgcn_readlane((int)ik, 16);
          uint32_t i2 = (uint32_t)__builtin_amdgcn_readlane((int)ik, 32);
          uint32_t i3 = (uint32_t)__builtin_amdgcn_readlane((int)ik, 48);
          wi = i0 < i1 ? i0 : i1;
          uint32_t wib = i2 < i3 ? i2 : i3;
          wi = wi < wib ? wi : wib;
        }
        wwm = wm; wwi = wi;
      }

      const int buf = t & 1;
      if (lane == 0) { rec[buf][wv].x = wwm; rec[buf][wv].y = wwi; }
      __syncthreads();

      uint2 r = rec[buf][lane & 15];
      uint32_t bm = r.x;
      DPP_ROR_U32_MAX(bm)
      uint32_t ci = (r.x == bm) ? r.y : 0xFFFFFFFFu;
      DPP_ROR_U32_MIN(ci)
      int sidx = __builtin_amdgcn_readfirstlane((int)ci);

      cx = XL[3 * sidx + 0];
      cy = XL[3 * sidx + 1];
      cz = XL[3 * sidx + 2];

      if (tid == 0) {
        float* rg = ring + (t & 15) * 3;
        rg[0] = cx; rg[1] = cy; rg[2] = cz;          // cheap ds_writes
        if ((t & 15) == 15) {                        // flush 16 centers
          float4* dst = (float4*)(new_xyz + ((size_t)b * NPT + (t - 15)) * 3);
          float4* src = (float4*)ring;
#pragma unroll
          for (int q = 0; q < 12; ++q) dst[q] = src[q];
          __hip_atomic_store(progress + b, t, __ATOMIC_RELEASE, __HIP_MEMORY_SCOPE_AGENT);
        }
      }
    }
  } else {
    // ================= worker role =================
    float* G    = (float*)SM;                 // 67 x 128
    float* H1   = (float*)(SM + 34304);       // 128 x 128
    int*   lidx = (int*)(SM + 99840);         // 4 x 32
    float* ctr  = (float*)(SM + 100352);      // 4 x 3

    const int wbid = blockIdx.x - 4;          // 0..251

    // ---- pre-phase: weights (block 4) + FT transpose slices (all workers)
    {
      if (wbid == 0) {
        for (int i = tid; i < 128 * 67; i += 1024) {
          int o = i / 67, c = i % 67;
          w1t[c * 128 + o] = w1[i];
        }
        for (int i = tid; i < 256 * 128; i += 1024) {
          int o = i >> 7, c = i & 127;
          w2t[c * 256 + o] = w2[i];
        }
      }
      float (*T)[65] = (float(*)[65])SM;      // 16.6 KB scratch (pre-G usage)
      for (int tile = wbid; tile < 512; tile += NWORK) {
        const int tb = tile >> 7;
        const int n0 = (tile & 127) << 6;
        const float* F = feat + (size_t)tb * CIN * NPTS;
        float* O = FT + (size_t)tb * NPTS * CIN;
#pragma unroll
        for (int p = 0; p < 4; ++p) {
          int c = p * 16 + (tid >> 6), ln = tid & 63;
          T[c][ln] = F[(size_t)c * NPTS + n0 + ln];
        }
        __syncthreads();
        {
          int j = tid >> 4, q = tid & 15;
          float4 v = make_float4(T[q * 4 + 0][j], T[q * 4 + 1][j],
                                 T[q * 4 + 2][j], T[q * 4 + 3][j]);
          *(float4*)&O[(size_t)(n0 + j) * CIN + q * 4] = v;
        }
        __syncthreads();
      }
      // publish our slice (release orders this block's prior writes)
      if (tid == 0)
        (void)__hip_atomic_fetch_add(ftflag, 1, __ATOMIC_RELEASE, __HIP_MEMORY_SCOPE_AGENT);
      // wait for all 252 slices (incl. weights)
      if (tid == 0) {
        while (__hip_atomic_load(ftflag, __ATOMIC_ACQUIRE, __HIP_MEMORY_SCOPE_AGENT) < NWORK)
          __builtin_amdgcn_s_sleep(2);
      }
      __syncthreads();
    }

    for (int qg = wbid; qg < NQUAD; qg += NWORK) {
      const int b = qg & 3;                   // quads ordered by squad -> readiness-monotone
      const int s0 = (qg >> 2) * 4;           // first center (in-batch), 4 per quad
      const float* X  = xyz + (size_t)b * NPTS * 3;
      const float* Fp = FT + (size_t)b * NPTS * CIN;

      // 1) wait for fps to produce centers s0..s0+3
      if (tid == 0) {
        while (__hip_atomic_load(progress + b, __ATOMIC_ACQUIRE, __HIP_MEMORY_SCOPE_AGENT) < s0 + 3)
          __builtin_amdgcn_s_sleep(2);
      }
      __syncthreads();

      // 2) centers -> LDS; ball query: one wave per center (waves 0..3)
      if (tid < 12) ctr[tid] = new_xyz[((size_t)b * NPT + s0) * 3 + tid];
      if (wv < 4) {
        const int s = s0 + wv;
        const float cx = new_xyz[((size_t)b * NPT + s) * 3 + 0];
        const float cy = new_xyz[((size_t)b * NPT + s) * 3 + 1];
        const float cz = new_xyz[((size_t)b * NPT + s) * 3 + 2];
        int* out = lidx + wv * NS;
        int found = 0;
        int first = -1;
        for (int base = 0; base < NPTS; base += 64) {
          const int p = base + lane;
          float x = X[p * 3 + 0], y = X[p * 3 + 1], z = X[p * 3 + 2];
          float dx = x - cx, dy = y - cy, dz = z - cz;
          float d2 = __fadd_rn(__fadd_rn(__fmul_rn(dx, dx), __fmul_rn(dy, dy)), __fmul_rn(dz, dz));
          unsigned long long mask = __ballot(d2 < R2);
          if (mask != 0ull && first < 0) first = base + __ffsll((unsigned long long)mask) - 1;
          if (found < NS) {
            if ((mask >> lane) & 1ull) {
              int rank = found + __popcll(mask & ((1ull << lane) - 1ull));
              if (rank < NS) out[rank] = p;
            }
          }
          found += __popcll(mask);
          if (found >= NS) break;
        }
        if (found < NS) {
          int pad = (first < 0) ? 0 : first;
          if (lane >= found && lane < NS) out[lane] = pad;
        }
      }
      __syncthreads();

      // 3) G fill: feature rows via point-major FT (coalesced), rel-xyz rows
      {
        int j = tid >> 3, q = tid & 7;       // 128 points x 8 chunks
        int p = lidx[j];
        const float4* row = (const float4*)(Fp + (size_t)p * CIN);
        float4 v0 = row[q * 2 + 0];
        float4 v1 = row[q * 2 + 1];
        float vs[8] = {v0.x, v0.y, v0.z, v0.w, v1.x, v1.y, v1.z, v1.w};
#pragma unroll
        for (int i = 0; i < 8; ++i)
          G[(3 + q * 8 + i) * 128 + j] = vs[i];
      }
      if (tid < 384) {
        int c = tid >> 7, j = tid & 127;
        int p = lidx[j];
        G[c * 128 + j] = X[p * 3 + c] - ctr[(j >> 5) * 3 + c];
      }
      __syncthreads();

      // 4) H1 = relu(W1 @ G + b1): 128 x 128, each thread 4o x 4j
      {
        const int oi = tid >> 5, ji = tid & 31;
        const int o0 = oi * 4, j0 = ji * 4;
        float acc[4][4];
#pragma unroll
        for (int i = 0; i < 4; ++i)
#pragma unroll
          for (int jj = 0; jj < 4; ++jj) acc[i][jj] = 0.f;
#pragma unroll 4
        for (int c = 0; c < 67; ++c) {
          float4 g  = *(const float4*)&G[c * 128 + j0];
          float4 wf = *(const float4*)&w1t[c * 128 + o0];
          float ga[4] = {g.x, g.y, g.z, g.w};
          float wa[4] = {wf.x, wf.y, wf.z, wf.w};
#pragma unroll
          for (int i = 0; i < 4; ++i)
#pragma unroll
            for (int jj = 0; jj < 4; ++jj)
              acc[i][jj] = fmaf(wa[i], ga[jj], acc[i][jj]);
        }
        float4 bb = *(const float4*)&b1[o0];
        float ba[4] = {bb.x, bb.y, bb.z, bb.w};
#pragma unroll
        for (int i = 0; i < 4; ++i) {
          float4 h;
          h.x = fmaxf(acc[i][0] + ba[i], 0.f);
          h.y = fmaxf(acc[i][1] + ba[i], 0.f);
          h.z = fmaxf(acc[i][2] + ba[i], 0.f);
          h.w = fmaxf(acc[i][3] + ba[i], 0.f);
          *(float4*)&H1[(o0 + i) * 128 + j0] = h;
        }
      }
      __syncthreads();

      // 5) H2 = relu(W2 @ H1 + b2): 256 x 128, thread 8o x 4j, then maxpool
      {
        const int oi = tid >> 5, ji = tid & 31;
        const int o0 = oi * 8, j0 = ji * 4;
        float acc[8][4];
#pragma unroll
        for (int i = 0; i < 8; ++i)
#pragma unroll
          for (int jj = 0; jj < 4; ++jj) acc[i][jj] = 0.f;
#pragma unroll 2
        for (int c = 0; c < 128; ++c) {
          float4 h  = *(const float4*)&H1[c * 128 + j0];
          float4 wa4 = *(const float4*)&w2t[c * 256 + o0];
          float4 wb4 = *(const float4*)&w2t[c * 256 + o0 + 4];
          float ha[4] = {h.x, h.y, h.z, h.w};
          float wa[8] = {wa4.x, wa4.y, wa4.z, wa4.w, wb4.x, wb4.y, wb4.z, wb4.w};
#pragma unroll
          for (int i = 0; i < 8; ++i)
#pragma unroll
            for (int jj = 0; jj < 4; ++jj)
              acc[i][jj] = fmaf(wa[i], ha[jj], acc[i][jj]);
        }
        float4 b2a = *(const float4*)&b2[o0];
        float4 b2b = *(const float4*)&b2[o0 + 4];
        float bb[8] = {b2a.x, b2a.y, b2a.z, b2a.w, b2b.x, b2b.y, b2b.z, b2b.w};
        float m[8];
#pragma unroll
        for (int i = 0; i < 8; ++i) {
          float v0 = fmaxf(acc[i][0] + bb[i], 0.f);
          float v1 = fmaxf(acc[i][1] + bb[i], 0.f);
          float v2 = fmaxf(acc[i][2] + bb[i], 0.f);
          float v3 = fmaxf(acc[i][3] + bb[i], 0.f);
          m[i] = fmaxf(fmaxf(v0, v1), fmaxf(v2, v3));
        }
        // ji&7 groups (8 lanes x 4 j = 32 samples = one center); xor 1,2,4
        // stays within each 8-lane group.
#pragma unroll
        for (int off = 1; off < 8; off <<= 1)
#pragma unroll
          for (int i = 0; i < 8; ++i) m[i] = fmaxf(m[i], __shfl_xor(m[i], off));
        if ((ji & 7) == 0) {
          int sidx = s0 + (ji >> 3);
#pragma unroll
          for (int i = 0; i < 8; ++i)
            pooled[((size_t)b * 256 + o0 + i) * (size_t)NPT + sidx] = m[i];
        }
      }
    }
  }
}

extern "C" void kernel_launch(void* const* d_in, const int* in_sizes, int n_in,
                              void* d_out, int out_size, void* d_ws, size_t ws_size,
                              hipStream_t stream) {
  (void)in_sizes; (void)n_in; (void)out_size; (void)ws_size;
  const float* xyz  = (const float*)d_in[0];   // (4,8192,3)
  const float* feat = (const float*)d_in[1];   // (4,64,8192)
  const float* w1   = (const float*)d_in[2];   // (128,67)
  const float* b1   = (const float*)d_in[3];   // (128)
  const float* w2   = (const float*)d_in[4];   // (256,128)
  const float* b2   = (const float*)d_in[5];   // (256)

  float* out     = (float*)d_out;
  float* new_xyz = out;                        // (4,2048,3)
  float* pooled  = out + (size_t)BATCH * NPT * 3;  // (4,256,2048)

  char* ws = (char*)d_ws;
  float* w1t      = (float*)ws;                       // 34304 B
  float* w2t      = (float*)(ws + 34304);             // 131072 B -> 165376
  float* FT       = (float*)(ws + 165376);            // 8388608 B -> 8553984
  int*   progress = (int*)(ws + 8553984);             // 32 B (progress[4] + ftflag)

  (void)hipMemsetAsync(progress, 0, 32, stream);
  fused_kernel<<<256, 1024, 0, stream>>>(xyz, feat, w1, b1, w2, b2,
                                         w1t, w2t, FT, new_xyz, pooled, progress);
}